// Round 16
// baseline (118.434 us; speedup 1.0000x reference)
//
#include <hip/hip_runtime.h>
#include <stdint.h>

#define B_ROWS 16384
#define C_CLS  2000
#define C_PAD  2048
#define F_DIM  1024
#define KT     16                        // K-tiles of 64
#define NRB    128                       // gemm row blocks (128 rows)
#define NCB    16                        // gemm col blocks (128 cols)
#define NPART  32                        // partial panels (col-64 granularity)
#define IMG_B  8192                      // 128 rows x 64 k fp8 = 4 frags x 2048 B
#define PANEL  ((size_t)KT * IMG_B)      // 128 KB per 128-row/col group

typedef float f32x16 __attribute__((ext_vector_type(16)));
typedef int   i32x4  __attribute__((ext_vector_type(4)));
typedef int   i32x8  __attribute__((ext_vector_type(8)));

#define SCALE_F 4.0f
#define SCALE_W 16.0f
#define INV_SCALE 0.015625f              // 1/64
#define SCL1 0x7F7F7F7F                  // E8M0 = 127 -> 2^0 = 1.0 per block

__device__ __forceinline__ void gl_lds16(const void* g, void* l) {
    __builtin_amdgcn_global_load_lds(
        (const __attribute__((address_space(1))) unsigned int*)g,
        (__attribute__((address_space(3))) unsigned int*)l, 16, 0, 0);
}

__device__ __forceinline__ unsigned int pk4(float a, float b, float c, float d) {
    int u = __builtin_amdgcn_cvt_pk_fp8_f32(a, b, 0, false);
    u = __builtin_amdgcn_cvt_pk_fp8_f32(c, d, u, true);
    return (unsigned int)u;
}

// MX 32x32x64 fragment (2048 B): lane l holds row (l&31), k-block (l>>5) (32 fp8).
// Chunk c (16 B, c = lane*2 + half) stored at physical slot pos(c) = c ^ ((c>>3)&7)
// (involution; uniform bank spread for the paired b128 reads at off0 / off0^16).
__device__ __forceinline__ int chpos(int c) { return c ^ ((c >> 3) & 7); }

// ---- fused prepass: blocks 0..511 = A (feat->fp8 + fisher), 512..639 = B (W->fp8 + bias) ----
__global__ __launch_bounds__(256)
void prep_kernel(const float* __restrict__ feat, const int* __restrict__ labels,
                 const float* __restrict__ centers, const float* __restrict__ W,
                 const float* __restrict__ bias,
                 char* __restrict__ A_pre, char* __restrict__ B_pre,
                 float* __restrict__ bias_pad, float* __restrict__ fisher_part)
{
    const int tid = threadIdx.x;
    if (blockIdx.x < 512) {
        const int rt = blockIdx.x >> 2, g = blockIdx.x & 3;
        const int r = tid >> 1, h = tid & 1;            // r = row in group, h = k-half (32)
        const int grow = rt * 128 + r;
        const int lab = labels[grow];
        const float* frow = feat    + (size_t)grow * F_DIM;
        const float* crow = centers + (size_t)lab  * F_DIM;
        const int frag = r >> 5;
        const int c0 = 2 * (h * 32 + (r & 31));          // first chunk index of this lane
        char* fbase = A_pre + (size_t)rt * PANEL + frag * 2048;
        float facc = 0.f;
        #pragma unroll
        for (int q = 0; q < 4; ++q) {
            const int kt = g * 4 + q;
            const int k0 = kt * 64 + h * 32;
            unsigned int o[8];
            #pragma unroll
            for (int c = 0; c < 8; ++c) {
                float4 av = *(const float4*)(frow + k0 + c * 4);
                float4 cv = *(const float4*)(crow + k0 + c * 4);
                float d0 = av.x - cv.x, d1 = av.y - cv.y, d2 = av.z - cv.z, d3 = av.w - cv.w;
                facc += d0 * d0 + d1 * d1 + d2 * d2 + d3 * d3;
                o[c] = pk4(SCALE_F * av.x, SCALE_F * av.y, SCALE_F * av.z, SCALE_F * av.w);
            }
            char* dst = fbase + (size_t)kt * IMG_B;
            *(uint4*)(dst + chpos(c0) * 16)     = (uint4){o[0], o[1], o[2], o[3]};
            *(uint4*)(dst + chpos(c0 + 1) * 16) = (uint4){o[4], o[5], o[6], o[7]};
        }
        for (int d = 32; d >= 1; d >>= 1) facc += __shfl_xor(facc, d);
        __shared__ float redw[4];
        const int wid = tid >> 6, ln = tid & 63;
        if (ln == 0) redw[wid] = facc;
        __syncthreads();
        if (tid == 0) fisher_part[blockIdx.x] = redw[0] + redw[1] + redw[2] + redw[3];
    } else {
        const int b = blockIdx.x - 512;
        const int ct = b >> 3, ktg = b & 7;              // ct = full 128-col panel index
        const int rcol = tid >> 1, h = tid & 1;
        const int gc = ct * 128 + rcol;
        const int frag = rcol >> 5;
        const int c0 = 2 * (h * 32 + (rcol & 31));
        char* fbase = B_pre + (size_t)ct * PANEL + frag * 2048;
        #pragma unroll
        for (int q = 0; q < 2; ++q) {
            const int kt = ktg * 2 + q;
            const int k0 = kt * 64 + h * 32;
            unsigned int o[8];
            if (gc < C_CLS) {
                const float* src = W + (size_t)gc * F_DIM + k0;
                #pragma unroll
                for (int c = 0; c < 8; ++c) {
                    float4 av = *(const float4*)(src + c * 4);
                    o[c] = pk4(SCALE_W * av.x, SCALE_W * av.y, SCALE_W * av.z, SCALE_W * av.w);
                }
            } else {
                #pragma unroll
                for (int c = 0; c < 8; ++c) o[c] = 0u;
            }
            char* dst = fbase + (size_t)kt * IMG_B;
            *(uint4*)(dst + chpos(c0) * 16)     = (uint4){o[0], o[1], o[2], o[3]};
            *(uint4*)(dst + chpos(c0 + 1) * 16) = (uint4){o[4], o[5], o[6], o[7]};
        }
        if (b < C_PAD / 256) {
            const int i = b * 256 + tid;
            bias_pad[i] = (i < C_CLS) ? bias[i] : -1e30f;
        }
    }
}

// ---- 128x128 MX-fp8 GEMM, m148 structure: gl_lds dbuf LDS, 1 barrier/K-step ----
__global__ __launch_bounds__(256, 2)
void gemm_kernel(const int* __restrict__ labels, const float* __restrict__ biasp,
                 const char* __restrict__ A_pre, const char* __restrict__ B_pre,
                 float* __restrict__ s_part, float* __restrict__ tl_part)
{
    __shared__ alignas(128) char smem[2][16384];   // [buf][A 8KB | B 8KB]

    const int cpx = gridDim.x >> 3;                // XCD swizzle: same-XCD blocks share rb
    const int wg = (blockIdx.x & 7) * cpx + (blockIdx.x >> 3);
    const int cb = wg & 15;
    const int rb = wg >> 4;

    const int tid = threadIdx.x;
    const int w = tid >> 6, lane = tid & 63;
    const int l31 = lane & 31, lh = lane >> 5;
    const int wr = w >> 1, wc = w & 1;             // 64x64 quadrant

    const char* Asrc = A_pre + (size_t)rb * PANEL;
    const char* Bsrc = B_pre + (size_t)cb * PANEL;

    const int off0 = chpos(2 * lane) * 16;         // paired reads at off0, off0^16

    f32x16 acc[2][2];
    #pragma unroll
    for (int mi = 0; mi < 2; ++mi)
        #pragma unroll
        for (int ni = 0; ni < 2; ++ni)
            #pragma unroll
            for (int e = 0; e < 16; ++e) acc[mi][ni][e] = 0.f;

#define STAGE(KTT, BUF) do {                                                          \
    const char* sa_ = Asrc + (size_t)(KTT) * IMG_B + tid * 16;                        \
    const char* sb_ = Bsrc + (size_t)(KTT) * IMG_B + tid * 16;                        \
    char* da_ = smem[BUF] + w * 1024;                                                 \
    gl_lds16(sa_,        da_);                                                        \
    gl_lds16(sa_ + 4096, da_ + 4096);                                                 \
    gl_lds16(sb_,        da_ + 8192);                                                 \
    gl_lds16(sb_ + 4096, da_ + 12288);                                                \
} while (0)

#define RDFRAG(DST, BASE) do {                                                        \
    *(i32x4*)&(DST)       = *(const i32x4*)((BASE) + off0);                           \
    *(((i32x4*)&(DST))+1) = *(const i32x4*)((BASE) + (off0 ^ 16));                    \
} while (0)

    STAGE(0, 0);
    __syncthreads();

    #pragma unroll 1
    for (int kt = 0; kt < KT; ++kt) {
        const int cur = kt & 1;
        if (kt + 1 < KT) STAGE(kt + 1, cur ^ 1);
        const char* Ab = smem[cur] + wr * 4096;            // frags 2wr, 2wr+1
        const char* Bb = smem[cur] + 8192 + wc * 4096;     // frags 2wc, 2wc+1
        i32x8 af[2], bf[2];
        RDFRAG(af[0], Ab);
        RDFRAG(af[1], Ab + 2048);
        RDFRAG(bf[0], Bb);
        RDFRAG(bf[1], Bb + 2048);
        __builtin_amdgcn_s_setprio(1);
        #pragma unroll
        for (int mi = 0; mi < 2; ++mi)
            #pragma unroll
            for (int ni = 0; ni < 2; ++ni)
                acc[mi][ni] = __builtin_amdgcn_mfma_scale_f32_32x32x64_f8f6f4(
                    af[mi], bf[ni], acc[mi][ni], 0, 0, 0, SCL1, 0, SCL1);
        __builtin_amdgcn_s_setprio(0);
        __syncthreads();
    }
#undef STAGE
#undef RDFRAG

    // epilogue: 32x32 C/D layout (col = lane&31, row = (reg&3)+8*(reg>>2)+4*(lane>>5))
    float bb[2];
    #pragma unroll
    for (int ni = 0; ni < 2; ++ni)
        bb[ni] = biasp[cb * 128 + wc * 64 + ni * 32 + l31];

    const int pidx = cb * 2 + wc;                  // 32 col-panels of 64
    #pragma unroll
    for (int mi = 0; mi < 2; ++mi) {
        #pragma unroll
        for (int reg = 0; reg < 16; ++reg) {
            const int rl = wr * 64 + mi * 32 + (reg & 3) + 8 * (reg >> 2) + 4 * lh;
            const int lab = labels[rb * 128 + rl];
            float sv = 0.f, tv = 0.f;
            #pragma unroll
            for (int ni = 0; ni < 2; ++ni) {
                const float v = fmaf(acc[mi][ni][reg], INV_SCALE, bb[ni]);
                sv += __expf(v);
                const int gc = cb * 128 + wc * 64 + ni * 32 + l31;
                tv = (gc == lab) ? v : tv;
            }
            #pragma unroll
            for (int d = 1; d < 32; d <<= 1) {
                sv += __shfl_xor(sv, d);
                tv += __shfl_xor(tv, d);
            }
            if (l31 == 0) {
                const int grow = rb * 128 + rl;
                s_part[(size_t)pidx * B_ROWS + grow]  = sv;
                tl_part[(size_t)pidx * B_ROWS + grow] = tv;
            }
        }
    }
}

// ---- combine partials across the 32 column panels, per-row aux loss ----
__global__ __launch_bounds__(256)
void rowcomb_kernel(const float* __restrict__ s_part, const float* __restrict__ tl_part,
                    float* __restrict__ aux_part)
{
    const int row = blockIdx.x * 256 + threadIdx.x;
    float s = 0.f, t = 0.f;
    #pragma unroll
    for (int p = 0; p < NPART; ++p) {
        s += s_part[(size_t)p * B_ROWS + row];
        t += tl_part[(size_t)p * B_ROWS + row];
    }
    float acc = __logf(s) - t;
    for (int d = 32; d >= 1; d >>= 1) acc += __shfl_xor(acc, d);
    __shared__ float red[4];
    const int wid = threadIdx.x >> 6, lane = threadIdx.x & 63;
    if (lane == 0) red[wid] = acc;
    __syncthreads();
    if (threadIdx.x == 0) aux_part[blockIdx.x] = red[0] + red[1] + red[2] + red[3];
}

__global__ __launch_bounds__(256)
void final_kernel(const float* __restrict__ fisher_part, const float* __restrict__ aux_part,
                  float* __restrict__ out)
{
    const int tid = threadIdx.x;
    float acc = fisher_part[tid] + fisher_part[256 + tid];
    if (tid < 64) acc += aux_part[tid];
    for (int d = 32; d >= 1; d >>= 1) acc += __shfl_xor(acc, d);
    __shared__ float red[4];
    const int wid = tid >> 6, lane = tid & 63;
    if (lane == 0) red[wid] = acc;
    __syncthreads();
    if (tid == 0) out[0] = (red[0] + red[1] + red[2] + red[3]) * (1.0f / (float)B_ROWS);
}

extern "C" void kernel_launch(void* const* d_in, const int* in_sizes, int n_in,
                              void* d_out, int out_size, void* d_ws, size_t ws_size,
                              hipStream_t stream)
{
    (void)in_sizes; (void)n_in; (void)out_size; (void)ws_size;
    const float* feat    = (const float*)d_in[0];
    const int*   labels  = (const int*)  d_in[1];
    const float* centers = (const float*)d_in[2];
    const float* W       = (const float*)d_in[3];
    const float* bias    = (const float*)d_in[4];
    float* out = (float*)d_out;
    char* ws = (char*)d_ws;

    const size_t szA    = (size_t)NRB * PANEL;   // 16,777,216
    const size_t szB    = (size_t)NCB * PANEL;   //  2,097,152
    const size_t szBias = (size_t)C_PAD * 4;
    const size_t szPart = (size_t)NPART * B_ROWS * 4;   // 2 MB each

    char* A_pre = ws;
    char* B_pre = ws + szA;
    float* bias_pad    = (float*)(ws + szA + szB);
    float* s_part      = (float*)(ws + szA + szB + szBias);
    float* tl_part     = (float*)(ws + szA + szB + szBias + szPart);
    float* fisher_part = (float*)(ws + szA + szB + szBias + 2 * szPart);
    float* aux_part    = fisher_part + 512;

    prep_kernel<<<640, 256, 0, stream>>>(feat, labels, centers, W, bias,
                                         A_pre, B_pre, bias_pad, fisher_part);
    gemm_kernel<<<NRB * NCB, 256, 0, stream>>>(labels, bias_pad, A_pre, B_pre, s_part, tl_part);
    rowcomb_kernel<<<B_ROWS / 256, 256, 0, stream>>>(s_part, tl_part, aux_part);
    final_kernel<<<1, 256, 0, stream>>>(fisher_part, aux_part, out);
}

// Round 17
// 117.530 us; speedup vs baseline: 1.0077x; 1.0077x over previous
//
#include <hip/hip_runtime.h>
#include <stdint.h>

#define B_ROWS 16384
#define C_CLS  2000
#define C_PAD  2048
#define F_DIM  1024
#define KT     16                        // K-tiles of 64
#define NRB    128                       // gemm row blocks (128 rows)
#define NCB    16                        // gemm col blocks (128 cols)
#define NPART  32                        // partial panels (col-64 granularity)
#define IMG_B  8192                      // 128 rows x 64 k fp8 = 4 frags x 2048 B
#define PANEL  ((size_t)KT * IMG_B)      // 128 KB per 128-row/col group

typedef float f32x16 __attribute__((ext_vector_type(16)));
typedef int   i32x4  __attribute__((ext_vector_type(4)));
typedef int   i32x8  __attribute__((ext_vector_type(8)));

#define SCALE_F 4.0f
#define SCALE_W 16.0f
#define INV_SCALE 0.015625f              // 1/64
#define SCL1 0x7F7F7F7F                  // E8M0 = 127 -> 2^0 = 1.0 per block

__device__ __forceinline__ unsigned int pk4(float a, float b, float c, float d) {
    int u = __builtin_amdgcn_cvt_pk_fp8_f32(a, b, 0, false);
    u = __builtin_amdgcn_cvt_pk_fp8_f32(c, d, u, true);
    return (unsigned int)u;
}

// MX 32x32x64 fragment (2048 B, linear): lane l holds row (l&31), k-block (l>>5)
// (32 contiguous fp8 at frag_base + l*32). Content verified on HW in R16 (absmax 0).

// ---- fused prepass: blocks 0..511 = A (feat->fp8 + fisher), 512..639 = B (W->fp8 + bias) ----
__global__ __launch_bounds__(256)
void prep_kernel(const float* __restrict__ feat, const int* __restrict__ labels,
                 const float* __restrict__ centers, const float* __restrict__ W,
                 const float* __restrict__ bias,
                 char* __restrict__ A_pre, char* __restrict__ B_pre,
                 float* __restrict__ bias_pad, float* __restrict__ fisher_part)
{
    const int tid = threadIdx.x;
    if (blockIdx.x < 512) {
        const int rt = blockIdx.x >> 2, g = blockIdx.x & 3;
        const int r = tid >> 1, h = tid & 1;            // r = row in group, h = k-half (32)
        const int grow = rt * 128 + r;
        const int lab = labels[grow];
        const float* frow = feat    + (size_t)grow * F_DIM;
        const float* crow = centers + (size_t)lab  * F_DIM;
        const int frag = r >> 5;
        const int c0 = 2 * (h * 32 + (r & 31));          // chunk index (linear)
        char* fbase = A_pre + (size_t)rt * PANEL + frag * 2048;
        float facc = 0.f;
        #pragma unroll
        for (int q = 0; q < 4; ++q) {
            const int kt = g * 4 + q;
            const int k0 = kt * 64 + h * 32;
            unsigned int o[8];
            #pragma unroll
            for (int c = 0; c < 8; ++c) {
                float4 av = *(const float4*)(frow + k0 + c * 4);
                float4 cv = *(const float4*)(crow + k0 + c * 4);
                float d0 = av.x - cv.x, d1 = av.y - cv.y, d2 = av.z - cv.z, d3 = av.w - cv.w;
                facc += d0 * d0 + d1 * d1 + d2 * d2 + d3 * d3;
                o[c] = pk4(SCALE_F * av.x, SCALE_F * av.y, SCALE_F * av.z, SCALE_F * av.w);
            }
            char* dst = fbase + (size_t)kt * IMG_B;
            *(uint4*)(dst + (size_t)c0 * 16)       = (uint4){o[0], o[1], o[2], o[3]};
            *(uint4*)(dst + (size_t)(c0 + 1) * 16) = (uint4){o[4], o[5], o[6], o[7]};
        }
        for (int d = 32; d >= 1; d >>= 1) facc += __shfl_xor(facc, d);
        __shared__ float redw[4];
        const int wid = tid >> 6, ln = tid & 63;
        if (ln == 0) redw[wid] = facc;
        __syncthreads();
        if (tid == 0) fisher_part[blockIdx.x] = redw[0] + redw[1] + redw[2] + redw[3];
    } else {
        const int b = blockIdx.x - 512;
        const int ct = b >> 3, ktg = b & 7;              // ct = full 128-col panel index
        const int rcol = tid >> 1, h = tid & 1;
        const int gc = ct * 128 + rcol;
        const int frag = rcol >> 5;
        const int c0 = 2 * (h * 32 + (rcol & 31));
        char* fbase = B_pre + (size_t)ct * PANEL + frag * 2048;
        #pragma unroll
        for (int q = 0; q < 2; ++q) {
            const int kt = ktg * 2 + q;
            const int k0 = kt * 64 + h * 32;
            unsigned int o[8];
            if (gc < C_CLS) {
                const float* src = W + (size_t)gc * F_DIM + k0;
                #pragma unroll
                for (int c = 0; c < 8; ++c) {
                    float4 av = *(const float4*)(src + c * 4);
                    o[c] = pk4(SCALE_W * av.x, SCALE_W * av.y, SCALE_W * av.z, SCALE_W * av.w);
                }
            } else {
                #pragma unroll
                for (int c = 0; c < 8; ++c) o[c] = 0u;
            }
            char* dst = fbase + (size_t)kt * IMG_B;
            *(uint4*)(dst + (size_t)c0 * 16)       = (uint4){o[0], o[1], o[2], o[3]};
            *(uint4*)(dst + (size_t)(c0 + 1) * 16) = (uint4){o[4], o[5], o[6], o[7]};
        }
        if (b < C_PAD / 256) {
            const int i = b * 256 + tid;
            bias_pad[i] = (i < C_CLS) ? bias[i] : -1e30f;
        }
    }
}

// ---- 128x128 MX-fp8 flat GEMM: 64x64 per wave, global->reg, 3 waves/SIMD ----
__global__ __launch_bounds__(256, 3)
void gemm_kernel(const int* __restrict__ labels, const float* __restrict__ biasp,
                 const char* __restrict__ A_pre, const char* __restrict__ B_pre,
                 float* __restrict__ s_part, float* __restrict__ tl_part)
{
    const int cpx = gridDim.x >> 3;                // XCD swizzle: same-XCD blocks share rb
    const int wg = (blockIdx.x & 7) * cpx + (blockIdx.x >> 3);
    const int cb = wg & 15;
    const int rb = wg >> 4;

    const int tid = threadIdx.x;
    const int w = tid >> 6, lane = tid & 63;
    const int l31 = lane & 31, lh = lane >> 5;
    const int wr = w >> 1, wc = w & 1;             // 64x64 wave tile

    const char* Apan = A_pre + (size_t)rb * PANEL + (wr * 2) * 2048 + lane * 32;
    const char* Bpan = B_pre + (size_t)cb * PANEL + (wc * 2) * 2048 + lane * 32;

    f32x16 acc[2][2];
    #pragma unroll
    for (int mi = 0; mi < 2; ++mi)
        #pragma unroll
        for (int ni = 0; ni < 2; ++ni)
            #pragma unroll
            for (int e = 0; e < 16; ++e) acc[mi][ni][e] = 0.f;

    i32x8 aE[2], bE[2], aO[2], bO[2];

#define LOAD32B(DST, P) do {                                                          \
    *(i32x4*)&(DST)       = *(const i32x4*)(P);                                       \
    *(((i32x4*)&(DST))+1) = *(const i32x4*)((P) + 16);                                \
} while (0)

#define LOADT(SA, SB, KTT) do {                                                       \
    const char* pa_ = Apan + (size_t)(KTT) * IMG_B;                                   \
    const char* pb_ = Bpan + (size_t)(KTT) * IMG_B;                                   \
    LOAD32B(SA[0], pa_);                                                              \
    LOAD32B(SA[1], pa_ + 2048);                                                       \
    LOAD32B(SB[0], pb_);                                                              \
    LOAD32B(SB[1], pb_ + 2048);                                                       \
} while (0)

#define MFMA4(SA, SB) do {                                                            \
    __builtin_amdgcn_s_setprio(1);                                                    \
    _Pragma("unroll")                                                                 \
    for (int mi_ = 0; mi_ < 2; ++mi_)                                                 \
        _Pragma("unroll")                                                             \
        for (int ni_ = 0; ni_ < 2; ++ni_)                                             \
            acc[mi_][ni_] = __builtin_amdgcn_mfma_scale_f32_32x32x64_f8f6f4(          \
                SA[mi_], SB[ni_], acc[mi_][ni_], 0, 0, 0, SCL1, 0, SCL1);             \
    __builtin_amdgcn_s_setprio(0);                                                    \
} while (0)

#define FENCE __builtin_amdgcn_sched_barrier(0)

    LOADT(aE, bE, 0);
    FENCE;
    #pragma unroll 1
    for (int k2 = 0; k2 < 7; ++k2) {
        LOADT(aO, bO, 2 * k2 + 1);      // issue next-tile loads first (latency cover)
        FENCE;
        MFMA4(aE, bE);                   // compiler inserts counted vmcnt before O-use
        FENCE;
        LOADT(aE, bE, 2 * k2 + 2);
        FENCE;
        MFMA4(aO, bO);
        FENCE;
    }
    LOADT(aO, bO, 15);
    FENCE;
    MFMA4(aE, bE);                       // tile 14
    MFMA4(aO, bO);                       // tile 15

#undef LOADT
#undef LOAD32B
#undef MFMA4
#undef FENCE

    // epilogue: 32x32 C/D layout (col = lane&31, row = (reg&3)+8*(reg>>2)+4*(lane>>5))
    float bb[2];
    #pragma unroll
    for (int ni = 0; ni < 2; ++ni)
        bb[ni] = biasp[cb * 128 + wc * 64 + ni * 32 + l31];

    const int pidx = cb * 2 + wc;                  // 32 col-panels of 64
    #pragma unroll
    for (int mi = 0; mi < 2; ++mi) {
        #pragma unroll
        for (int reg = 0; reg < 16; ++reg) {
            const int rl = wr * 64 + mi * 32 + (reg & 3) + 8 * (reg >> 2) + 4 * lh;
            const int lab = labels[rb * 128 + rl];
            float sv = 0.f, tv = 0.f;
            #pragma unroll
            for (int ni = 0; ni < 2; ++ni) {
                const float v = fmaf(acc[mi][ni][reg], INV_SCALE, bb[ni]);
                sv += __expf(v);
                const int gc = cb * 128 + wc * 64 + ni * 32 + l31;
                tv = (gc == lab) ? v : tv;
            }
            #pragma unroll
            for (int d = 1; d < 32; d <<= 1) {
                sv += __shfl_xor(sv, d);
                tv += __shfl_xor(tv, d);
            }
            if (l31 == 0) {
                const int grow = rb * 128 + rl;
                s_part[(size_t)pidx * B_ROWS + grow]  = sv;
                tl_part[(size_t)pidx * B_ROWS + grow] = tv;
            }
        }
    }
}

// ---- combine partials across the 32 column panels, per-row aux loss ----
__global__ __launch_bounds__(256)
void rowcomb_kernel(const float* __restrict__ s_part, const float* __restrict__ tl_part,
                    float* __restrict__ aux_part)
{
    const int row = blockIdx.x * 256 + threadIdx.x;
    float s = 0.f, t = 0.f;
    #pragma unroll
    for (int p = 0; p < NPART; ++p) {
        s += s_part[(size_t)p * B_ROWS + row];
        t += tl_part[(size_t)p * B_ROWS + row];
    }
    float acc = __logf(s) - t;
    for (int d = 32; d >= 1; d >>= 1) acc += __shfl_xor(acc, d);
    __shared__ float red[4];
    const int wid = threadIdx.x >> 6, lane = threadIdx.x & 63;
    if (lane == 0) red[wid] = acc;
    __syncthreads();
    if (threadIdx.x == 0) aux_part[blockIdx.x] = red[0] + red[1] + red[2] + red[3];
}

__global__ __launch_bounds__(256)
void final_kernel(const float* __restrict__ fisher_part, const float* __restrict__ aux_part,
                  float* __restrict__ out)
{
    const int tid = threadIdx.x;
    float acc = fisher_part[tid] + fisher_part[256 + tid];
    if (tid < 64) acc += aux_part[tid];
    for (int d = 32; d >= 1; d >>= 1) acc += __shfl_xor(acc, d);
    __shared__ float red[4];
    const int wid = tid >> 6, lane = tid & 63;
    if (lane == 0) red[wid] = acc;
    __syncthreads();
    if (tid == 0) out[0] = (red[0] + red[1] + red[2] + red[3]) * (1.0f / (float)B_ROWS);
}

extern "C" void kernel_launch(void* const* d_in, const int* in_sizes, int n_in,
                              void* d_out, int out_size, void* d_ws, size_t ws_size,
                              hipStream_t stream)
{
    (void)in_sizes; (void)n_in; (void)out_size; (void)ws_size;
    const float* feat    = (const float*)d_in[0];
    const int*   labels  = (const int*)  d_in[1];
    const float* centers = (const float*)d_in[2];
    const float* W       = (const float*)d_in[3];
    const float* bias    = (const float*)d_in[4];
    float* out = (float*)d_out;
    char* ws = (char*)d_ws;

    const size_t szA    = (size_t)NRB * PANEL;   // 16,777,216
    const size_t szB    = (size_t)NCB * PANEL;   //  2,097,152
    const size_t szBias = (size_t)C_PAD * 4;
    const size_t szPart = (size_t)NPART * B_ROWS * 4;   // 2 MB each

    char* A_pre = ws;
    char* B_pre = ws + szA;
    float* bias_pad    = (float*)(ws + szA + szB);
    float* s_part      = (float*)(ws + szA + szB + szBias);
    float* tl_part     = (float*)(ws + szA + szB + szBias + szPart);
    float* fisher_part = (float*)(ws + szA + szB + szBias + 2 * szPart);
    float* aux_part    = fisher_part + 512;

    prep_kernel<<<640, 256, 0, stream>>>(feat, labels, centers, W, bias,
                                         A_pre, B_pre, bias_pad, fisher_part);
    gemm_kernel<<<NRB * NCB, 256, 0, stream>>>(labels, bias_pad, A_pre, B_pre, s_part, tl_part);
    rowcomb_kernel<<<B_ROWS / 256, 256, 0, stream>>>(s_part, tl_part, aux_part);
    final_kernel<<<1, 256, 0, stream>>>(fisher_part, aux_part, out);
}

// Round 19
// 92.368 us; speedup vs baseline: 1.2822x; 1.2724x over previous
//
#include <hip/hip_runtime.h>
#include <stdint.h>

#define B_ROWS 16384
#define C_CLS  2000
#define C_PAD  2048
#define F_DIM  1024
#define KT     16                         // K-tiles of 64
#define NRB    64                         // gemm row blocks (256 rows)
#define NCBP   16                         // gemm col panels (128 cols)
#define PANEL_A 262144                    // 16 kt x 16 frags x 1024 B
#define PANEL_BB 131072                   // 16 kt x 8 frags x 1024 B
#define NPASS  2                          // persistent passes (1024 virtual blocks / 512)

typedef float f32x4 __attribute__((ext_vector_type(4)));
typedef long long i64x2 __attribute__((ext_vector_type(2)));

#define SCALE_F 4.0f
#define SCALE_W 16.0f
#define INV_SCALE 0.015625f               // 1/64

__device__ __forceinline__ unsigned int pk4(float a, float b, float c, float d) {
    int u = __builtin_amdgcn_cvt_pk_fp8_f32(a, b, 0, false);   // bytes 0,1
    u = __builtin_amdgcn_cvt_pk_fp8_f32(c, d, u, true);        // bytes 2,3
    return (unsigned int)u;
}

// Fragment-linear panels: frag f covers rows f*16..+16; lane l at byte l*16 of the
// 1024B frag; 16B = k[lhi*8..+8) ∪ [32+lhi*8..+8) (i64x2 = [kf0,kf1]) — R10/R11-verified.

// ---- fused prepass: blocks 0..511 = A (feat->fp8 + fisher), 512..639 = B (W->fp8 + bias) ----
__global__ __launch_bounds__(256)
void prep_kernel(const float* __restrict__ feat, const int* __restrict__ labels,
                 const float* __restrict__ centers, const float* __restrict__ W,
                 const float* __restrict__ bias,
                 char* __restrict__ A_pre, char* __restrict__ B_pre,
                 float* __restrict__ bias_pad, float* __restrict__ fisher_part)
{
    const int tid = threadIdx.x;
    if (blockIdx.x < 512) {
        const int rt = blockIdx.x >> 2, g = blockIdx.x & 3;   // rt: 128-row half-panels
        const int rb = rt >> 1;
        const int r = tid >> 1, h = tid & 1;
        const int grow = rt * 128 + r;
        const int lab = labels[grow];
        const float* frow = feat    + (size_t)grow * F_DIM;
        const float* crow = centers + (size_t)lab  * F_DIM;
        const int frag = (rt & 1) * 8 + (r >> 4);
        char* pan = A_pre + (size_t)rb * PANEL_A + frag * 1024 + (r & 15) * 16;
        float facc = 0.f;
        #pragma unroll
        for (int q = 0; q < 4; ++q) {
            const int kt = g * 4 + q;
            #pragma unroll
            for (int u = 0; u < 2; ++u) {
                const int lhi = h * 2 + u;
                const int k0 = kt * 64 + lhi * 8;
                float4 a0 = *(const float4*)(frow + k0);
                float4 a1 = *(const float4*)(frow + k0 + 4);
                float4 a2 = *(const float4*)(frow + k0 + 32);
                float4 a3 = *(const float4*)(frow + k0 + 36);
                float4 c0 = *(const float4*)(crow + k0);
                float4 c1 = *(const float4*)(crow + k0 + 4);
                float4 c2 = *(const float4*)(crow + k0 + 32);
                float4 c3 = *(const float4*)(crow + k0 + 36);
                float d0 = a0.x-c0.x, d1 = a0.y-c0.y, d2 = a0.z-c0.z, d3 = a0.w-c0.w;
                float d4 = a1.x-c1.x, d5 = a1.y-c1.y, d6 = a1.z-c1.z, d7 = a1.w-c1.w;
                facc += d0*d0 + d1*d1 + d2*d2 + d3*d3 + d4*d4 + d5*d5 + d6*d6 + d7*d7;
                d0 = a2.x-c2.x; d1 = a2.y-c2.y; d2 = a2.z-c2.z; d3 = a2.w-c2.w;
                d4 = a3.x-c3.x; d5 = a3.y-c3.y; d6 = a3.z-c3.z; d7 = a3.w-c3.w;
                facc += d0*d0 + d1*d1 + d2*d2 + d3*d3 + d4*d4 + d5*d5 + d6*d6 + d7*d7;
                uint4 o = { pk4(SCALE_F*a0.x, SCALE_F*a0.y, SCALE_F*a0.z, SCALE_F*a0.w),
                            pk4(SCALE_F*a1.x, SCALE_F*a1.y, SCALE_F*a1.z, SCALE_F*a1.w),
                            pk4(SCALE_F*a2.x, SCALE_F*a2.y, SCALE_F*a2.z, SCALE_F*a2.w),
                            pk4(SCALE_F*a3.x, SCALE_F*a3.y, SCALE_F*a3.z, SCALE_F*a3.w) };
                *(uint4*)(pan + kt * 16384 + lhi * 256) = o;
            }
        }
        for (int d = 32; d >= 1; d >>= 1) facc += __shfl_xor(facc, d);
        __shared__ float redw[4];
        const int wid = tid >> 6, lane = tid & 63;
        if (lane == 0) redw[wid] = facc;
        __syncthreads();
        if (tid == 0) fisher_part[blockIdx.x] = redw[0] + redw[1] + redw[2] + redw[3];
    } else {
        const int b = blockIdx.x - 512;
        const int ct = b >> 3, ktg = b & 7;
        const int rcol = tid >> 1, h = tid & 1;
        const int gc = ct * 128 + rcol;
        char* pan = B_pre + (size_t)ct * PANEL_BB + (rcol >> 4) * 1024 + (rcol & 15) * 16;
        #pragma unroll
        for (int q = 0; q < 2; ++q) {
            const int kt = ktg * 2 + q;
            #pragma unroll
            for (int u = 0; u < 2; ++u) {
                const int lhi = h * 2 + u;
                uint4 o;
                if (gc < C_CLS) {
                    const float* src = W + (size_t)gc * F_DIM + kt * 64 + lhi * 8;
                    float4 a0 = *(const float4*)(src);
                    float4 a1 = *(const float4*)(src + 4);
                    float4 a2 = *(const float4*)(src + 32);
                    float4 a3 = *(const float4*)(src + 36);
                    o = (uint4){ pk4(SCALE_W*a0.x, SCALE_W*a0.y, SCALE_W*a0.z, SCALE_W*a0.w),
                                 pk4(SCALE_W*a1.x, SCALE_W*a1.y, SCALE_W*a1.z, SCALE_W*a1.w),
                                 pk4(SCALE_W*a2.x, SCALE_W*a2.y, SCALE_W*a2.z, SCALE_W*a2.w),
                                 pk4(SCALE_W*a3.x, SCALE_W*a3.y, SCALE_W*a3.z, SCALE_W*a3.w) };
                } else {
                    o = (uint4){0u, 0u, 0u, 0u};
                }
                *(uint4*)(pan + kt * 8192 + lhi * 256) = o;
            }
        }
        if (b < C_PAD / 256) {
            const int i = b * 256 + tid;
            bias_pad[i] = (i < C_CLS) ? bias[i] : -1e30f;
        }
    }
}

// ---- 256x128 fp8 flat-MFMA GEMM, persistent 2-pass: global->reg, zero LDS in K-loop,
// ---- next-pass tile prefetched under the epilogue ----
__global__ __launch_bounds__(256, 2)
void gemm_kernel(const int* __restrict__ labels, const float* __restrict__ biasp,
                 const char* __restrict__ A_pre, const char* __restrict__ B_pre,
                 float* __restrict__ s_part, float* __restrict__ tl_part)
{
    const int tid = threadIdx.x;
    const int w = tid >> 6, lane = tid & 63;
    const int l15 = lane & 15, lhi = lane >> 4;

    const int aoff = w * 4096 + lane * 16;
    const int boff = lane * 16;

    f32x4 acc[4][8];
    #pragma unroll
    for (int mi = 0; mi < 4; ++mi)
        #pragma unroll
        for (int ni = 0; ni < 8; ++ni) acc[mi][ni] = (f32x4){0.f, 0.f, 0.f, 0.f};

    i64x2 aE[4], bE[8], aO[4], bO[8];

#define LOADT(SA, SB, PA, PB, KTT) do {                                               \
    const char* pa_ = (PA) + (size_t)(KTT) * 16384;                                   \
    const char* pb_ = (PB) + (size_t)(KTT) * 8192;                                    \
    _Pragma("unroll")                                                                 \
    for (int i_ = 0; i_ < 4; ++i_) SA[i_] = *(const i64x2*)(pa_ + i_ * 1024);         \
    _Pragma("unroll")                                                                 \
    for (int i_ = 0; i_ < 8; ++i_) SB[i_] = *(const i64x2*)(pb_ + i_ * 1024);         \
} while (0)

#define MFMA64(SA, SB) do {                                                           \
    __builtin_amdgcn_s_setprio(1);                                                    \
    _Pragma("unroll")                                                                 \
    for (int kf_ = 0; kf_ < 2; ++kf_)                                                 \
        _Pragma("unroll")                                                             \
        for (int mi_ = 0; mi_ < 4; ++mi_)                                             \
            _Pragma("unroll")                                                         \
            for (int ni_ = 0; ni_ < 8; ++ni_)                                         \
                acc[mi_][ni_] = __builtin_amdgcn_mfma_f32_16x16x32_fp8_fp8(           \
                    SA[mi_][kf_], SB[ni_][kf_], acc[mi_][ni_], 0, 0, 0);              \
    __builtin_amdgcn_s_setprio(0);                                                    \
} while (0)

#define FENCE __builtin_amdgcn_sched_barrier(0)

    // virtual-block mapping: 1024 tiles, vb = pass*512 + bid, wg = (vb&7)*128 + (vb>>3)
    // (bijective: 512 % 8 == 0 -> vb&7 = bid&7; vb>>3 = pass*64 + (bid>>3) in [0,128))
    int vb = blockIdx.x;                         // pass 0
    int wg = (vb & 7) * 128 + (vb >> 3);
    int cb = wg & 15;
    int rb = wg >> 4;
    const char* Apan = A_pre + (size_t)rb * PANEL_A + aoff;
    const char* Bpan = B_pre + (size_t)cb * PANEL_BB + boff;

    LOADT(aE, bE, Apan, Bpan, 0);
    FENCE;

    #pragma unroll 1
    for (int pass = 0; pass < NPASS; ++pass) {
        #pragma unroll 1
        for (int k2 = 0; k2 < 7; ++k2) {
            LOADT(aO, bO, Apan, Bpan, 2 * k2 + 1);   // next-tile loads first (latency cover)
            FENCE;
            MFMA64(aE, bE);
            FENCE;
            LOADT(aE, bE, Apan, Bpan, 2 * k2 + 2);
            FENCE;
            MFMA64(aO, bO);
            FENCE;
        }
        LOADT(aO, bO, Apan, Bpan, 15);
        FENCE;
        MFMA64(aE, bE);                      // tile 14
        FENCE;
        // prefetch next pass's tile 0 under tile-15 MFMA + epilogue
        int cbn = cb, rbn = rb;
        const char *ApanN = Apan, *BpanN = Bpan;
        if (pass + 1 < NPASS) {
            const int vbn = (pass + 1) * 512 + blockIdx.x;
            const int wgn = (vbn & 7) * 128 + (vbn >> 3);
            cbn = wgn & 15;
            rbn = wgn >> 4;
            ApanN = A_pre + (size_t)rbn * PANEL_A + aoff;
            BpanN = B_pre + (size_t)cbn * PANEL_BB + boff;
            LOADT(aE, bE, ApanN, BpanN, 0);
        }
        FENCE;
        MFMA64(aO, bO);                      // tile 15
        FENCE;

        // epilogue: each wave owns full 128-col rows -> no cross-wave reduce
        float bb[8];
        #pragma unroll
        for (int ni = 0; ni < 8; ++ni)
            bb[ni] = biasp[cb * 128 + ni * 16 + l15];

        #pragma unroll
        for (int mi = 0; mi < 4; ++mi) {
            #pragma unroll
            for (int j = 0; j < 4; ++j) {
                const int rl = w * 64 + mi * 16 + lhi * 4 + j;
                const int lab = labels[rb * 256 + rl];
                float sv = 0.f, tv = 0.f;
                #pragma unroll
                for (int ni = 0; ni < 8; ++ni) {
                    const float v = fmaf(acc[mi][ni][j], INV_SCALE, bb[ni]);
                    sv += __expf(v);
                    const int gc = cb * 128 + ni * 16 + l15;
                    tv = (gc == lab) ? v : tv;
                }
                #pragma unroll
                for (int d = 1; d < 16; d <<= 1) {
                    sv += __shfl_xor(sv, d);
                    tv += __shfl_xor(tv, d);
                }
                if (l15 == 0) {
                    const int grow = rb * 256 + rl;
                    s_part[(size_t)cb * B_ROWS + grow]  = sv;
                    tl_part[(size_t)cb * B_ROWS + grow] = tv;
                }
            }
        }

        if (pass + 1 < NPASS) {
            #pragma unroll
            for (int mi = 0; mi < 4; ++mi)
                #pragma unroll
                for (int ni = 0; ni < 8; ++ni) acc[mi][ni] = (f32x4){0.f, 0.f, 0.f, 0.f};
            cb = cbn; rb = rbn; Apan = ApanN; Bpan = BpanN;
        }
    }

#undef LOADT
#undef MFMA64
#undef FENCE
}

// ---- combine partials across the 16 column panels, per-row aux loss ----
__global__ __launch_bounds__(256)
void rowcomb_kernel(const float* __restrict__ s_part, const float* __restrict__ tl_part,
                    float* __restrict__ aux_part)
{
    const int row = blockIdx.x * 256 + threadIdx.x;
    float s = 0.f, t = 0.f;
    #pragma unroll
    for (int p = 0; p < NCBP; ++p) {
        s += s_part[(size_t)p * B_ROWS + row];
        t += tl_part[(size_t)p * B_ROWS + row];
    }
    float acc = __logf(s) - t;
    for (int d = 32; d >= 1; d >>= 1) acc += __shfl_xor(acc, d);
    __shared__ float red[4];
    const int wid = threadIdx.x >> 6, lane = threadIdx.x & 63;
    if (lane == 0) red[wid] = acc;
    __syncthreads();
    if (threadIdx.x == 0) aux_part[blockIdx.x] = red[0] + red[1] + red[2] + red[3];
}

__global__ __launch_bounds__(256)
void final_kernel(const float* __restrict__ fisher_part, const float* __restrict__ aux_part,
                  float* __restrict__ out)
{
    const int tid = threadIdx.x;
    float acc = fisher_part[tid] + fisher_part[256 + tid];
    if (tid < 64) acc += aux_part[tid];
    for (int d = 32; d >= 1; d >>= 1) acc += __shfl_xor(acc, d);
    __shared__ float red[4];
    const int wid = tid >> 6, lane = tid & 63;
    if (lane == 0) red[wid] = acc;
    __syncthreads();
    if (tid == 0) out[0] = (red[0] + red[1] + red[2] + red[3]) * (1.0f / (float)B_ROWS);
}

extern "C" void kernel_launch(void* const* d_in, const int* in_sizes, int n_in,
                              void* d_out, int out_size, void* d_ws, size_t ws_size,
                              hipStream_t stream)
{
    (void)in_sizes; (void)n_in; (void)out_size; (void)ws_size;
    const float* feat    = (const float*)d_in[0];
    const int*   labels  = (const int*)  d_in[1];
    const float* centers = (const float*)d_in[2];
    const float* W       = (const float*)d_in[3];
    const float* bias    = (const float*)d_in[4];
    float* out = (float*)d_out;
    char* ws = (char*)d_ws;

    const size_t szA    = (size_t)NRB  * PANEL_A;   // 16,777,216
    const size_t szB    = (size_t)NCBP * PANEL_BB;  //  2,097,152
    const size_t szBias = (size_t)C_PAD * 4;

    char* A_pre = ws;
    char* B_pre = ws + szA;
    float* bias_pad    = (float*)(ws + szA + szB);
    float* s_part      = (float*)(ws + szA + szB + szBias);
    float* tl_part     = s_part + (size_t)NCBP * B_ROWS;
    float* fisher_part = tl_part + (size_t)NCBP * B_ROWS;
    float* aux_part    = fisher_part + 512;

    prep_kernel<<<640, 256, 0, stream>>>(feat, labels, centers, W, bias,
                                         A_pre, B_pre, bias_pad, fisher_part);
    gemm_kernel<<<512, 256, 0, stream>>>(labels, bias_pad, A_pre, B_pre, s_part, tl_part);
    rowcomb_kernel<<<B_ROWS / 256, 256, 0, stream>>>(s_part, tl_part, aux_part);
    final_kernel<<<1, 256, 0, stream>>>(fisher_part, aux_part, out);
}